// Round 1
// baseline (5679.556 us; speedup 1.0000x reference)
//
#include <hip/hip_runtime.h>

// GCN 2-layer forward, MI355X. Round 1: fp32 atomic-scatter baseline.
// N=100000 nodes, E=1600000 edges, D=128 throughout.

#define NN 100000
#define NE 1600000
#define DD 128

// ---------------- small utility kernels ----------------

__global__ __launch_bounds__(256) void zero_f32(float* __restrict__ p, int n) {
  int i = blockIdx.x * 256 + threadIdx.x;
  if (i < n) p[i] = 0.0f;
}

__global__ __launch_bounds__(256) void deg_scatter(const int* __restrict__ edst,
                                                   float* __restrict__ deg) {
  int e = blockIdx.x * 256 + threadIdx.x;
  if (e < NE) atomicAdd(&deg[edst[e]], 1.0f);
}

__global__ __launch_bounds__(256) void finalize_dinv(float* __restrict__ deg) {
  int i = blockIdx.x * 256 + threadIdx.x;
  if (i < NN) deg[i] = rsqrtf(deg[i] + 1.0f);  // deg includes self-loop (+1)
}

// ---------------- GEMM: H[M,128] = X[M,128] @ W[128,128] ----------------
// Block = 256 threads computes a 32-row x 128-col tile. K staged in chunks of 32.
// thread: tx = t&31 -> cols tx*4..tx*4+3 ; ty = t>>5 -> rows ty*4..ty*4+3
__global__ __launch_bounds__(256) void gemm128(const float* __restrict__ X,
                                               const float* __restrict__ W,
                                               float* __restrict__ H) {
  __shared__ float ws_[32][128];   // W chunk [k][c], rows 512B -> b128 reads conflict-free
  __shared__ float xs[32][33];     // X tile  [r][k], pad 33 breaks bank aliasing
  const int t = threadIdx.x;
  const int tx = t & 31;
  const int ty = t >> 5;
  const int row0 = blockIdx.x * 32;  // 100000 = 32*3125, exact
  float acc[4][4] = {{0.f, 0.f, 0.f, 0.f}, {0.f, 0.f, 0.f, 0.f},
                     {0.f, 0.f, 0.f, 0.f}, {0.f, 0.f, 0.f, 0.f}};
  for (int kc = 0; kc < 128; kc += 32) {
    // stage W chunk: 32x128 floats = 1024 float4, 4 per thread, coalesced
#pragma unroll
    for (int i = 0; i < 4; ++i) {
      int idx = i * 256 + t;
      int kk = idx >> 5;
      int c4 = idx & 31;
      *(float4*)&ws_[kk][c4 * 4] = *(const float4*)&W[(kc + kk) * 128 + c4 * 4];
    }
    // stage X tile: 32 rows x 32 k = 256 float4, 1 per thread, coalesced
    {
      int r = t >> 3;
      int c4 = t & 7;
      float4 v = *(const float4*)&X[(row0 + r) * 128 + kc + c4 * 4];
      xs[r][c4 * 4 + 0] = v.x;
      xs[r][c4 * 4 + 1] = v.y;
      xs[r][c4 * 4 + 2] = v.z;
      xs[r][c4 * 4 + 3] = v.w;
    }
    __syncthreads();
#pragma unroll
    for (int k = 0; k < 32; ++k) {
      float a0 = xs[ty * 4 + 0][k];
      float a1 = xs[ty * 4 + 1][k];
      float a2 = xs[ty * 4 + 2][k];
      float a3 = xs[ty * 4 + 3][k];
      float4 wv = *(float4*)&ws_[k][tx * 4];
      acc[0][0] += a0 * wv.x; acc[0][1] += a0 * wv.y; acc[0][2] += a0 * wv.z; acc[0][3] += a0 * wv.w;
      acc[1][0] += a1 * wv.x; acc[1][1] += a1 * wv.y; acc[1][2] += a1 * wv.z; acc[1][3] += a1 * wv.w;
      acc[2][0] += a2 * wv.x; acc[2][1] += a2 * wv.y; acc[2][2] += a2 * wv.z; acc[2][3] += a2 * wv.w;
      acc[3][0] += a3 * wv.x; acc[3][1] += a3 * wv.y; acc[3][2] += a3 * wv.z; acc[3][3] += a3 * wv.w;
    }
    __syncthreads();
  }
#pragma unroll
  for (int i = 0; i < 4; ++i) {
    float4 o = make_float4(acc[i][0], acc[i][1], acc[i][2], acc[i][3]);
    *(float4*)&H[(row0 + ty * 4 + i) * 128 + tx * 4] = o;
  }
}

// ---------------- aggregation ----------------

// agg[i][:] = h[i][:] * dinv[i]^2   (self-loop term; also zero-initializes agg)
__global__ __launch_bounds__(256) void init_agg(const float* __restrict__ H,
                                                const float* __restrict__ dinv,
                                                float* __restrict__ agg) {
  int gid = blockIdx.x * 256 + threadIdx.x;  // over NN*32, exact (12500 blocks)
  int row = gid >> 5;
  int lane = gid & 31;
  float di = dinv[row];
  float c = di * di;
  float4 v = *(const float4*)&H[row * DD + lane * 4];
  v.x *= c; v.y *= c; v.z *= c; v.w *= c;
  *(float4*)&agg[row * DD + lane * 4] = v;
}

// per-edge: agg[dst][:] += h[src][:] * dinv[src]*dinv[dst]   (32 lanes/edge, float4)
__global__ __launch_bounds__(256) void scatter_edges(const float* __restrict__ H,
                                                     const int* __restrict__ esrc,
                                                     const int* __restrict__ edst,
                                                     const float* __restrict__ dinv,
                                                     float* __restrict__ agg) {
  int gid = blockIdx.x * 256 + threadIdx.x;  // over NE*32, exact (200000 blocks)
  int lane = gid & 31;
  int e = gid >> 5;
  int s = esrc[e];
  int d = edst[e];
  float coef = dinv[s] * dinv[d];
  float4 v = *(const float4*)&H[s * DD + lane * 4];
  float* p = agg + d * DD + lane * 4;
  atomicAdd(p + 0, v.x * coef);
  atomicAdd(p + 1, v.y * coef);
  atomicAdd(p + 2, v.z * coef);
  atomicAdd(p + 3, v.w * coef);
}

// out[i][d] = relu(agg[i][d] + b[d])  (in-place allowed: src==dst)
__global__ __launch_bounds__(256) void bias_relu(const float* __restrict__ agg,
                                                 const float* __restrict__ b,
                                                 float* __restrict__ out) {
  int gid = blockIdx.x * 256 + threadIdx.x;  // over NN*32
  int lane = gid & 31;
  float4 bv = *(const float4*)&b[lane * 4];
  float4 v = *(const float4*)&agg[gid * 4];
  v.x = fmaxf(v.x + bv.x, 0.f);
  v.y = fmaxf(v.y + bv.y, 0.f);
  v.z = fmaxf(v.z + bv.z, 0.f);
  v.w = fmaxf(v.w + bv.w, 0.f);
  *(float4*)&out[gid * 4] = v;
}

// ---------------- launch ----------------

extern "C" void kernel_launch(void* const* d_in, const int* in_sizes, int n_in,
                              void* d_out, int out_size, void* d_ws, size_t ws_size,
                              hipStream_t stream) {
  const float* x  = (const float*)d_in[0];
  const int*   ei = (const int*)d_in[1];   // [2][NE] int32
  const float* W1 = (const float*)d_in[2];
  const float* b1 = (const float*)d_in[3];
  const float* W2 = (const float*)d_in[4];
  const float* b2 = (const float*)d_in[5];
  float* out = (float*)d_out;

  const int* esrc = ei;
  const int* edst = ei + NE;

  // workspace layout: dinv (128K floats, padded) | A (N*D) | B (N*D)
  float* dinv = (float*)d_ws;
  float* A = dinv + 131072;
  float* B = A + NN * DD;

  // degrees -> dinv
  zero_f32<<<(NN + 255) / 256, 256, 0, stream>>>(dinv, NN);
  deg_scatter<<<(NE + 255) / 256, 256, 0, stream>>>(edst, dinv);
  finalize_dinv<<<(NN + 255) / 256, 256, 0, stream>>>(dinv);

  // layer 1: A = x @ W1 ; B = aggregate(A) ; B = relu(B + b1)
  gemm128<<<NN / 32, 256, 0, stream>>>(x, W1, A);
  init_agg<<<NN * 32 / 256, 256, 0, stream>>>(A, dinv, B);
  scatter_edges<<<NE * 32 / 256, 256, 0, stream>>>(A, esrc, edst, dinv, B);
  bias_relu<<<NN * 32 / 256, 256, 0, stream>>>(B, b1, B);

  // layer 2: A = B @ W2 ; out = aggregate(A) ; out = relu(out + b2)
  gemm128<<<NN / 32, 256, 0, stream>>>(B, W2, A);
  init_agg<<<NN * 32 / 256, 256, 0, stream>>>(A, dinv, out);
  scatter_edges<<<NE * 32 / 256, 256, 0, stream>>>(A, esrc, edst, dinv, out);
  bias_relu<<<NN * 32 / 256, 256, 0, stream>>>(out, b2, out);
}

// Round 2
// 600.993 us; speedup vs baseline: 9.4503x; 9.4503x over previous
//
#include <hip/hip_runtime.h>

// GCN 2-layer forward, MI355X. Round 2: CSR gather-reduce (no float atomics).
// N=100000 nodes, E=1600000 edges, D=128 throughout.

#define NN 100000
#define NE 1600000
#define DD 128
#define SCAN_NB 391  // ceil(NN/256)

// ---------------- degree / dinv ----------------

__global__ __launch_bounds__(256) void zero_i32(int* __restrict__ p, int n) {
  int i = blockIdx.x * 256 + threadIdx.x;
  if (i < n) p[i] = 0;
}

__global__ __launch_bounds__(256) void deg_count(const int* __restrict__ edst,
                                                 int* __restrict__ cnt) {
  int e = blockIdx.x * 256 + threadIdx.x;
  if (e < NE) atomicAdd(&cnt[edst[e]], 1);
}

__global__ __launch_bounds__(256) void finalize_dinv(const int* __restrict__ cnt,
                                                     float* __restrict__ dinv) {
  int i = blockIdx.x * 256 + threadIdx.x;
  if (i < NN) dinv[i] = rsqrtf((float)cnt[i] + 1.0f);  // +1 = self-loop
}

// ---------------- exclusive scan of cnt -> rowptr (3-kernel, 2-level) ----------------

__global__ __launch_bounds__(256) void scan_block_sums(const int* __restrict__ cnt,
                                                       int* __restrict__ bsum) {
  __shared__ int s[256];
  int t = threadIdx.x;
  int i = blockIdx.x * 256 + t;
  s[t] = (i < NN) ? cnt[i] : 0;
  __syncthreads();
  for (int off = 128; off > 0; off >>= 1) {
    if (t < off) s[t] += s[t + off];
    __syncthreads();
  }
  if (t == 0) bsum[blockIdx.x] = s[0];
}

__global__ __launch_bounds__(512) void scan_partials(int* __restrict__ bsum) {
  // single block: exclusive scan of SCAN_NB (<512) partials, in place
  __shared__ int s[512];
  int t = threadIdx.x;
  int v = (t < SCAN_NB) ? bsum[t] : 0;
  s[t] = v;
  __syncthreads();
  for (int off = 1; off < 512; off <<= 1) {
    int a = (t >= off) ? s[t - off] : 0;
    __syncthreads();
    s[t] += a;
    __syncthreads();
  }
  if (t < SCAN_NB) bsum[t] = s[t] - v;  // exclusive
}

__global__ __launch_bounds__(256) void scan_write(const int* __restrict__ cnt,
                                                  const int* __restrict__ bsum,
                                                  int* __restrict__ rowptr,
                                                  int* __restrict__ cursor) {
  __shared__ int s[256];
  int t = threadIdx.x;
  int i = blockIdx.x * 256 + t;
  int v = (i < NN) ? cnt[i] : 0;
  s[t] = v;
  __syncthreads();
  for (int off = 1; off < 256; off <<= 1) {
    int a = (t >= off) ? s[t - off] : 0;
    __syncthreads();
    s[t] += a;
    __syncthreads();
  }
  int excl = s[t] - v + bsum[blockIdx.x];
  if (i < NN) {
    rowptr[i] = excl;
    cursor[i] = excl;
  }
  if (i == NN - 1) rowptr[NN] = excl + v;  // == NE
}

// ---------------- CSR build: sort edges by dst (counting sort) ----------------

__global__ __launch_bounds__(256) void build_csr(const int* __restrict__ esrc,
                                                 const int* __restrict__ edst,
                                                 const float* __restrict__ dinv,
                                                 int* __restrict__ cursor,
                                                 int* __restrict__ col,
                                                 float* __restrict__ coefv) {
  int e = blockIdx.x * 256 + threadIdx.x;
  if (e < NE) {
    int s = esrc[e];
    int d = edst[e];
    int pos = atomicAdd(&cursor[d], 1);
    col[pos] = s;
    coefv[pos] = dinv[s] * dinv[d];
  }
}

// ---------------- GEMM: H[M,128] = X[M,128] @ W[128,128] ----------------
__global__ __launch_bounds__(256) void gemm128(const float* __restrict__ X,
                                               const float* __restrict__ W,
                                               float* __restrict__ H) {
  __shared__ float ws_[32][128];
  __shared__ float xs[32][33];
  const int t = threadIdx.x;
  const int tx = t & 31;
  const int ty = t >> 5;
  const int row0 = blockIdx.x * 32;  // 100000 = 32*3125, exact
  float acc[4][4] = {{0.f, 0.f, 0.f, 0.f}, {0.f, 0.f, 0.f, 0.f},
                     {0.f, 0.f, 0.f, 0.f}, {0.f, 0.f, 0.f, 0.f}};
  for (int kc = 0; kc < 128; kc += 32) {
#pragma unroll
    for (int i = 0; i < 4; ++i) {
      int idx = i * 256 + t;
      int kk = idx >> 5;
      int c4 = idx & 31;
      *(float4*)&ws_[kk][c4 * 4] = *(const float4*)&W[(kc + kk) * 128 + c4 * 4];
    }
    {
      int r = t >> 3;
      int c4 = t & 7;
      float4 v = *(const float4*)&X[(row0 + r) * 128 + kc + c4 * 4];
      xs[r][c4 * 4 + 0] = v.x;
      xs[r][c4 * 4 + 1] = v.y;
      xs[r][c4 * 4 + 2] = v.z;
      xs[r][c4 * 4 + 3] = v.w;
    }
    __syncthreads();
#pragma unroll
    for (int k = 0; k < 32; ++k) {
      float a0 = xs[ty * 4 + 0][k];
      float a1 = xs[ty * 4 + 1][k];
      float a2 = xs[ty * 4 + 2][k];
      float a3 = xs[ty * 4 + 3][k];
      float4 wv = *(float4*)&ws_[k][tx * 4];
      acc[0][0] += a0 * wv.x; acc[0][1] += a0 * wv.y; acc[0][2] += a0 * wv.z; acc[0][3] += a0 * wv.w;
      acc[1][0] += a1 * wv.x; acc[1][1] += a1 * wv.y; acc[1][2] += a1 * wv.z; acc[1][3] += a1 * wv.w;
      acc[2][0] += a2 * wv.x; acc[2][1] += a2 * wv.y; acc[2][2] += a2 * wv.z; acc[2][3] += a2 * wv.w;
      acc[3][0] += a3 * wv.x; acc[3][1] += a3 * wv.y; acc[3][2] += a3 * wv.z; acc[3][3] += a3 * wv.w;
    }
    __syncthreads();
  }
#pragma unroll
  for (int i = 0; i < 4; ++i) {
    float4 o = make_float4(acc[i][0], acc[i][1], acc[i][2], acc[i][3]);
    *(float4*)&H[(row0 + ty * 4 + i) * 128 + tx * 4] = o;
  }
}

// ---------------- fused aggregate: out = relu(D^-1/2 A D^-1/2 H + b) ----------------
// 32 lanes per node; each lane owns 4 contiguous cols (float4).
__global__ __launch_bounds__(256) void aggregate(const float* __restrict__ H,
                                                 const int* __restrict__ rowptr,
                                                 const int* __restrict__ col,
                                                 const float* __restrict__ coefv,
                                                 const float* __restrict__ dinv,
                                                 const float* __restrict__ bias,
                                                 float* __restrict__ out) {
  int gid = blockIdx.x * 256 + threadIdx.x;  // NN*32 threads, exact
  int node = gid >> 5;
  int lane = gid & 31;

  float di = dinv[node];
  float sc = di * di;  // self-loop coef
  float4 acc = *(const float4*)&H[node * DD + lane * 4];
  acc.x *= sc; acc.y *= sc; acc.z *= sc; acc.w *= sc;

  int e = rowptr[node];
  int e1 = rowptr[node + 1];
  for (; e + 1 < e1; e += 2) {  // 2-way unroll for load ILP
    int s0 = col[e];
    int s1 = col[e + 1];
    float c0 = coefv[e];
    float c1 = coefv[e + 1];
    float4 v0 = *(const float4*)&H[s0 * DD + lane * 4];
    float4 v1 = *(const float4*)&H[s1 * DD + lane * 4];
    acc.x += c0 * v0.x + c1 * v1.x;
    acc.y += c0 * v0.y + c1 * v1.y;
    acc.z += c0 * v0.z + c1 * v1.z;
    acc.w += c0 * v0.w + c1 * v1.w;
  }
  if (e < e1) {
    int s0 = col[e];
    float c0 = coefv[e];
    float4 v0 = *(const float4*)&H[s0 * DD + lane * 4];
    acc.x += c0 * v0.x;
    acc.y += c0 * v0.y;
    acc.z += c0 * v0.z;
    acc.w += c0 * v0.w;
  }

  float4 bv = *(const float4*)&bias[lane * 4];
  acc.x = fmaxf(acc.x + bv.x, 0.f);
  acc.y = fmaxf(acc.y + bv.y, 0.f);
  acc.z = fmaxf(acc.z + bv.z, 0.f);
  acc.w = fmaxf(acc.w + bv.w, 0.f);
  *(float4*)&out[node * DD + lane * 4] = acc;
}

// ---------------- launch ----------------

extern "C" void kernel_launch(void* const* d_in, const int* in_sizes, int n_in,
                              void* d_out, int out_size, void* d_ws, size_t ws_size,
                              hipStream_t stream) {
  const float* x  = (const float*)d_in[0];
  const int*   ei = (const int*)d_in[1];  // [2][NE] int32
  const float* W1 = (const float*)d_in[2];
  const float* b1 = (const float*)d_in[3];
  const float* W2 = (const float*)d_in[4];
  const float* b2 = (const float*)d_in[5];
  float* out = (float*)d_out;

  const int* esrc = ei;
  const int* edst = ei + NE;

  // workspace layout (all 4-byte elems, 64 MB total < ws):
  char* w = (char*)d_ws;
  int*   cnt    = (int*)w;            w += ((NN + 1023) & ~1023) * 4;       // 100352
  float* dinv   = (float*)w;          w += ((NN + 1023) & ~1023) * 4;
  int*   rowptr = (int*)w;            w += ((NN + 1 + 1023) & ~1023) * 4;
  int*   cursor = (int*)w;            w += ((NN + 1023) & ~1023) * 4;
  int*   bsum   = (int*)w;            w += 512 * 4;
  int*   col    = (int*)w;            w += (size_t)NE * 4;
  float* coefv  = (float*)w;          w += (size_t)NE * 4;
  float* A      = (float*)w;          // NN*DD floats

  const int nb_n = (NN + 255) / 256;
  const int nb_e = (NE + 255) / 256;

  // degrees -> dinv ; CSR build (shared by both layers)
  zero_i32<<<nb_n, 256, 0, stream>>>(cnt, NN);
  deg_count<<<nb_e, 256, 0, stream>>>(edst, cnt);
  finalize_dinv<<<nb_n, 256, 0, stream>>>(cnt, dinv);
  scan_block_sums<<<SCAN_NB, 256, 0, stream>>>(cnt, bsum);
  scan_partials<<<1, 512, 0, stream>>>(bsum);
  scan_write<<<SCAN_NB, 256, 0, stream>>>(cnt, bsum, rowptr, cursor);
  build_csr<<<nb_e, 256, 0, stream>>>(esrc, edst, dinv, cursor, col, coefv);

  // layer 1: A = x @ W1 ; out = relu(aggregate(A) + b1)
  gemm128<<<NN / 32, 256, 0, stream>>>(x, W1, A);
  aggregate<<<NN * 32 / 256, 256, 0, stream>>>(A, rowptr, col, coefv, dinv, b1, out);

  // layer 2: A = out @ W2 ; out = relu(aggregate(A) + b2)
  gemm128<<<NN / 32, 256, 0, stream>>>(out, W2, A);
  aggregate<<<NN * 32 / 256, 256, 0, stream>>>(A, rowptr, col, coefv, dinv, b2, out);
}

// Round 4
// 574.058 us; speedup vs baseline: 9.8937x; 1.0469x over previous
//
#include <hip/hip_runtime.h>

// GCN 2-layer forward, MI355X. Round 3 (resubmit after infra timeout):
// faster GEMM (4x8/thread, b128 LDS), fused 8B edge records, 4-way unrolled gather.
// N=100000 nodes, E=1600000 edges, D=128 throughout.

#define NN 100000
#define NE 1600000
#define DD 128
#define SCAN_NB 391  // ceil(NN/256)

// ---------------- degree / dinv ----------------

__global__ __launch_bounds__(256) void zero_i32(int* __restrict__ p, int n) {
  int i = blockIdx.x * 256 + threadIdx.x;
  if (i < n) p[i] = 0;
}

__global__ __launch_bounds__(256) void deg_count(const int* __restrict__ edst,
                                                 int* __restrict__ cnt) {
  int e = blockIdx.x * 256 + threadIdx.x;
  if (e < NE) atomicAdd(&cnt[edst[e]], 1);
}

__global__ __launch_bounds__(256) void finalize_dinv(const int* __restrict__ cnt,
                                                     float* __restrict__ dinv) {
  int i = blockIdx.x * 256 + threadIdx.x;
  if (i < NN) dinv[i] = rsqrtf((float)cnt[i] + 1.0f);  // +1 = self-loop
}

// ---------------- exclusive scan of cnt -> rowptr ----------------

__global__ __launch_bounds__(256) void scan_block_sums(const int* __restrict__ cnt,
                                                       int* __restrict__ bsum) {
  __shared__ int s[256];
  int t = threadIdx.x;
  int i = blockIdx.x * 256 + t;
  s[t] = (i < NN) ? cnt[i] : 0;
  __syncthreads();
  for (int off = 128; off > 0; off >>= 1) {
    if (t < off) s[t] += s[t + off];
    __syncthreads();
  }
  if (t == 0) bsum[blockIdx.x] = s[0];
}

__global__ __launch_bounds__(512) void scan_partials(int* __restrict__ bsum) {
  __shared__ int s[512];
  int t = threadIdx.x;
  int v = (t < SCAN_NB) ? bsum[t] : 0;
  s[t] = v;
  __syncthreads();
  for (int off = 1; off < 512; off <<= 1) {
    int a = (t >= off) ? s[t - off] : 0;
    __syncthreads();
    s[t] += a;
    __syncthreads();
  }
  if (t < SCAN_NB) bsum[t] = s[t] - v;  // exclusive
}

__global__ __launch_bounds__(256) void scan_write(const int* __restrict__ cnt,
                                                  const int* __restrict__ bsum,
                                                  int* __restrict__ rowptr,
                                                  int* __restrict__ cursor) {
  __shared__ int s[256];
  int t = threadIdx.x;
  int i = blockIdx.x * 256 + t;
  int v = (i < NN) ? cnt[i] : 0;
  s[t] = v;
  __syncthreads();
  for (int off = 1; off < 256; off <<= 1) {
    int a = (t >= off) ? s[t - off] : 0;
    __syncthreads();
    s[t] += a;
    __syncthreads();
  }
  int excl = s[t] - v + bsum[blockIdx.x];
  if (i < NN) {
    rowptr[i] = excl;
    cursor[i] = excl;
  }
  if (i == NN - 1) rowptr[NN] = excl + v;  // == NE
}

// ---------------- CSR build: fused {src, coef} 8-byte records ----------------

__global__ __launch_bounds__(256) void build_csr(const int* __restrict__ esrc,
                                                 const int* __restrict__ edst,
                                                 const float* __restrict__ dinv,
                                                 int* __restrict__ cursor,
                                                 int2* __restrict__ cc) {
  int e = blockIdx.x * 256 + threadIdx.x;
  if (e < NE) {
    int s = esrc[e];
    int d = edst[e];
    int pos = atomicAdd(&cursor[d], 1);
    cc[pos] = make_int2(s, __float_as_int(dinv[s] * dinv[d]));
  }
}

// ---------------- GEMM: H[M,128] = X[M,128] @ W[128,128] ----------------
// 64-row x 128-col tile per block (256 thr). Thread (tx=t&15, ty=t>>4):
// rows ty*4..+3, cols {tx*4..+3, 64+tx*4..+3}. K staged in chunks of 32.
__global__ __launch_bounds__(256) void gemm128(const float* __restrict__ X,
                                               const float* __restrict__ W,
                                               float* __restrict__ H) {
  __shared__ float ws2[32][128];  // [k][c]
  __shared__ float xs[64][36];    // [r][k], stride 36 floats (144B, 16B-aligned)
  const int t = threadIdx.x;
  const int tx = t & 15;
  const int ty = t >> 4;
  const int row0 = blockIdx.x * 64;  // grid 1563, last block partially OOB
  float acc[4][8];
#pragma unroll
  for (int i = 0; i < 4; ++i)
#pragma unroll
    for (int j = 0; j < 8; ++j) acc[i][j] = 0.f;

  for (int kc = 0; kc < 128; kc += 32) {
    // stage W chunk: 32x128 = 1024 float4, 4/thread, coalesced
#pragma unroll
    for (int i = 0; i < 4; ++i) {
      int idx = i * 256 + t;
      int kk = idx >> 5;
      int c4 = idx & 31;
      *(float4*)&ws2[kk][c4 * 4] = *(const float4*)&W[(kc + kk) * 128 + c4 * 4];
    }
    // stage X tile: 64 rows x 32 k = 512 float4, 2/thread, coalesced (row-clamped)
#pragma unroll
    for (int i = 0; i < 2; ++i) {
      int idx = i * 256 + t;
      int r = idx >> 3;
      int c4 = idx & 7;
      int grow = row0 + r;
      if (grow > NN - 1) grow = NN - 1;  // clamp, harmless re-read
      *(float4*)&xs[r][c4 * 4] = *(const float4*)&X[grow * 128 + kc + c4 * 4];
    }
    __syncthreads();
#pragma unroll
    for (int kk = 0; kk < 32; kk += 4) {
      float4 a0 = *(float4*)&xs[ty * 4 + 0][kk];
      float4 a1 = *(float4*)&xs[ty * 4 + 1][kk];
      float4 a2 = *(float4*)&xs[ty * 4 + 2][kk];
      float4 a3 = *(float4*)&xs[ty * 4 + 3][kk];
#pragma unroll
      for (int j = 0; j < 4; ++j) {
        float4 b0 = *(float4*)&ws2[kk + j][tx * 4];
        float4 b1 = *(float4*)&ws2[kk + j][64 + tx * 4];
        float a[4] = {j == 0 ? a0.x : j == 1 ? a0.y : j == 2 ? a0.z : a0.w,
                      j == 0 ? a1.x : j == 1 ? a1.y : j == 2 ? a1.z : a1.w,
                      j == 0 ? a2.x : j == 1 ? a2.y : j == 2 ? a2.z : a2.w,
                      j == 0 ? a3.x : j == 1 ? a3.y : j == 2 ? a3.z : a3.w};
#pragma unroll
        for (int i = 0; i < 4; ++i) {
          acc[i][0] += a[i] * b0.x;
          acc[i][1] += a[i] * b0.y;
          acc[i][2] += a[i] * b0.z;
          acc[i][3] += a[i] * b0.w;
          acc[i][4] += a[i] * b1.x;
          acc[i][5] += a[i] * b1.y;
          acc[i][6] += a[i] * b1.z;
          acc[i][7] += a[i] * b1.w;
        }
      }
    }
    __syncthreads();
  }
#pragma unroll
  for (int i = 0; i < 4; ++i) {
    int row = row0 + ty * 4 + i;
    if (row < NN) {
      float4 o0 = make_float4(acc[i][0], acc[i][1], acc[i][2], acc[i][3]);
      float4 o1 = make_float4(acc[i][4], acc[i][5], acc[i][6], acc[i][7]);
      *(float4*)&H[row * 128 + tx * 4] = o0;
      *(float4*)&H[row * 128 + 64 + tx * 4] = o1;
    }
  }
}

// ---------------- fused aggregate: out = relu(D^-1/2 A D^-1/2 H + b) ----------------
// 32 lanes per node; lane owns 4 contiguous cols (float4). 4-way unrolled gather.
__global__ __launch_bounds__(256) void aggregate(const float* __restrict__ H,
                                                 const int* __restrict__ rowptr,
                                                 const int2* __restrict__ cc,
                                                 const float* __restrict__ dinv,
                                                 const float* __restrict__ bias,
                                                 float* __restrict__ out) {
  int gid = blockIdx.x * 256 + threadIdx.x;  // NN*32 threads, exact
  int node = gid >> 5;
  int lane = gid & 31;

  float di = dinv[node];
  float sc = di * di;  // self-loop coef
  float4 acc = *(const float4*)&H[node * DD + lane * 4];
  acc.x *= sc; acc.y *= sc; acc.z *= sc; acc.w *= sc;

  int e = rowptr[node];
  int e1 = rowptr[node + 1];
  for (; e + 3 < e1; e += 4) {
    int2 m0 = cc[e + 0];
    int2 m1 = cc[e + 1];
    int2 m2 = cc[e + 2];
    int2 m3 = cc[e + 3];
    float4 v0 = *(const float4*)&H[m0.x * DD + lane * 4];
    float4 v1 = *(const float4*)&H[m1.x * DD + lane * 4];
    float4 v2 = *(const float4*)&H[m2.x * DD + lane * 4];
    float4 v3 = *(const float4*)&H[m3.x * DD + lane * 4];
    float c0 = __int_as_float(m0.y);
    float c1 = __int_as_float(m1.y);
    float c2 = __int_as_float(m2.y);
    float c3 = __int_as_float(m3.y);
    acc.x += c0 * v0.x + c1 * v1.x + c2 * v2.x + c3 * v3.x;
    acc.y += c0 * v0.y + c1 * v1.y + c2 * v2.y + c3 * v3.y;
    acc.z += c0 * v0.z + c1 * v1.z + c2 * v2.z + c3 * v3.z;
    acc.w += c0 * v0.w + c1 * v1.w + c2 * v2.w + c3 * v3.w;
  }
  for (; e < e1; ++e) {
    int2 m = cc[e];
    float c = __int_as_float(m.y);
    float4 v = *(const float4*)&H[m.x * DD + lane * 4];
    acc.x += c * v.x;
    acc.y += c * v.y;
    acc.z += c * v.z;
    acc.w += c * v.w;
  }

  float4 bv = *(const float4*)&bias[lane * 4];
  acc.x = fmaxf(acc.x + bv.x, 0.f);
  acc.y = fmaxf(acc.y + bv.y, 0.f);
  acc.z = fmaxf(acc.z + bv.z, 0.f);
  acc.w = fmaxf(acc.w + bv.w, 0.f);
  *(float4*)&out[node * DD + lane * 4] = acc;
}

// ---------------- launch ----------------

extern "C" void kernel_launch(void* const* d_in, const int* in_sizes, int n_in,
                              void* d_out, int out_size, void* d_ws, size_t ws_size,
                              hipStream_t stream) {
  const float* x  = (const float*)d_in[0];
  const int*   ei = (const int*)d_in[1];  // [2][NE] int32
  const float* W1 = (const float*)d_in[2];
  const float* b1 = (const float*)d_in[3];
  const float* W2 = (const float*)d_in[4];
  const float* b2 = (const float*)d_in[5];
  float* out = (float*)d_out;

  const int* esrc = ei;
  const int* edst = ei + NE;

  // workspace layout (offsets in bytes, all 4KB-aligned):
  char* w = (char*)d_ws;
  int*   cnt    = (int*)w;    w += ((NN + 1023) & ~1023) * 4;
  float* dinv   = (float*)w;  w += ((NN + 1023) & ~1023) * 4;
  int*   rowptr = (int*)w;    w += ((NN + 1 + 1023) & ~1023) * 4;
  int*   cursor = (int*)w;    w += ((NN + 1023) & ~1023) * 4;
  int*   bsum   = (int*)w;    w += 512 * 4;
  int2*  cc     = (int2*)w;   w += (size_t)NE * 8;
  float* A      = (float*)w;  // NN*DD floats

  const int nb_n = (NN + 255) / 256;
  const int nb_e = (NE + 255) / 256;

  // degrees -> dinv ; CSR build (shared by both layers)
  zero_i32<<<nb_n, 256, 0, stream>>>(cnt, NN);
  deg_count<<<nb_e, 256, 0, stream>>>(edst, cnt);
  finalize_dinv<<<nb_n, 256, 0, stream>>>(cnt, dinv);
  scan_block_sums<<<SCAN_NB, 256, 0, stream>>>(cnt, bsum);
  scan_partials<<<1, 512, 0, stream>>>(bsum);
  scan_write<<<SCAN_NB, 256, 0, stream>>>(cnt, bsum, rowptr, cursor);
  build_csr<<<nb_e, 256, 0, stream>>>(esrc, edst, dinv, cursor, cc);

  // layer 1: A = x @ W1 ; out = relu(aggregate(A) + b1)
  gemm128<<<(NN + 63) / 64, 256, 0, stream>>>(x, W1, A);
  aggregate<<<NN * 32 / 256, 256, 0, stream>>>(A, rowptr, cc, dinv, b1, out);

  // layer 2: A = out @ W2 ; out = relu(aggregate(A) + b2)
  gemm128<<<(NN + 63) / 64, 256, 0, stream>>>(out, W2, A);
  aggregate<<<NN * 32 / 256, 256, 0, stream>>>(A, rowptr, cc, dinv, b2, out);
}

// Round 5
// 535.837 us; speedup vs baseline: 10.5994x; 1.0713x over previous
//
#include <hip/hip_runtime.h>

// GCN 2-layer forward, MI355X. Round 5: G = dinv*H prescale (no per-edge coef),
// 4B col-only edge records, atomic-free CSR placement, fused dinv epilogues.
// N=100000 nodes, E=1600000 edges, D=128 throughout.

#define NN 100000
#define NE 1600000
#define DD 128
#define SCAN_NB 391  // ceil(NN/256)

// ---------------- degree(+rank) / scan / dinv ----------------

__global__ __launch_bounds__(256) void zero_i32(int* __restrict__ p, int n) {
  int i = blockIdx.x * 256 + threadIdx.x;
  if (i < n) p[i] = 0;
}

// rank[e] = arrival index of edge e at its destination; cnt[d] = in-degree
__global__ __launch_bounds__(256) void deg_rank(const int* __restrict__ edst,
                                                int* __restrict__ cnt,
                                                int* __restrict__ rank) {
  int e = blockIdx.x * 256 + threadIdx.x;
  if (e < NE) rank[e] = atomicAdd(&cnt[edst[e]], 1);
}

__global__ __launch_bounds__(256) void scan_block_sums(const int* __restrict__ cnt,
                                                       int* __restrict__ bsum) {
  __shared__ int s[256];
  int t = threadIdx.x;
  int i = blockIdx.x * 256 + t;
  s[t] = (i < NN) ? cnt[i] : 0;
  __syncthreads();
  for (int off = 128; off > 0; off >>= 1) {
    if (t < off) s[t] += s[t + off];
    __syncthreads();
  }
  if (t == 0) bsum[blockIdx.x] = s[0];
}

__global__ __launch_bounds__(512) void scan_partials(int* __restrict__ bsum) {
  __shared__ int s[512];
  int t = threadIdx.x;
  int v = (t < SCAN_NB) ? bsum[t] : 0;
  s[t] = v;
  __syncthreads();
  for (int off = 1; off < 512; off <<= 1) {
    int a = (t >= off) ? s[t - off] : 0;
    __syncthreads();
    s[t] += a;
    __syncthreads();
  }
  if (t < SCAN_NB) bsum[t] = s[t] - v;  // exclusive
}

// rowptr (exclusive scan) + dinv = rsqrt(deg+1), fused
__global__ __launch_bounds__(256) void scan_write(const int* __restrict__ cnt,
                                                  const int* __restrict__ bsum,
                                                  int* __restrict__ rowptr,
                                                  float* __restrict__ dinv) {
  __shared__ int s[256];
  int t = threadIdx.x;
  int i = blockIdx.x * 256 + t;
  int v = (i < NN) ? cnt[i] : 0;
  s[t] = v;
  __syncthreads();
  for (int off = 1; off < 256; off <<= 1) {
    int a = (t >= off) ? s[t - off] : 0;
    __syncthreads();
    s[t] += a;
    __syncthreads();
  }
  int excl = s[t] - v + bsum[blockIdx.x];
  if (i < NN) {
    rowptr[i] = excl;
    dinv[i] = rsqrtf((float)v + 1.0f);  // +1 = self-loop
  }
  if (i == NN - 1) rowptr[NN] = excl + v;  // == NE
}

// ---------------- CSR placement: col[rowptr[d]+rank[e]] = src (no atomics) ----------------

__global__ __launch_bounds__(256) void build_csr(const int* __restrict__ esrc,
                                                 const int* __restrict__ edst,
                                                 const int* __restrict__ rank,
                                                 const int* __restrict__ rowptr,
                                                 int* __restrict__ col) {
  int e = blockIdx.x * 256 + threadIdx.x;
  if (e < NE) col[rowptr[edst[e]] + rank[e]] = esrc[e];
}

// ---------------- GEMM: G[M,128] = dinv[m] * (X[M,128] @ W[128,128]) ----------------
// 64-row x 128-col tile per block (256 thr). Thread (tx=t&15, ty=t>>4):
// rows ty*4..+3, cols {tx*4..+3, 64+tx*4..+3}. K staged in chunks of 32.
__global__ __launch_bounds__(256) void gemm128(const float* __restrict__ X,
                                               const float* __restrict__ W,
                                               const float* __restrict__ dinv,
                                               float* __restrict__ G) {
  __shared__ float ws2[32][128];  // [k][c]
  __shared__ float xs[64][36];    // [r][k], stride 36 floats
  const int t = threadIdx.x;
  const int tx = t & 15;
  const int ty = t >> 4;
  const int row0 = blockIdx.x * 64;  // grid 1563, last block partially OOB
  float acc[4][8];
#pragma unroll
  for (int i = 0; i < 4; ++i)
#pragma unroll
    for (int j = 0; j < 8; ++j) acc[i][j] = 0.f;

  for (int kc = 0; kc < 128; kc += 32) {
#pragma unroll
    for (int i = 0; i < 4; ++i) {
      int idx = i * 256 + t;
      int kk = idx >> 5;
      int c4 = idx & 31;
      *(float4*)&ws2[kk][c4 * 4] = *(const float4*)&W[(kc + kk) * 128 + c4 * 4];
    }
#pragma unroll
    for (int i = 0; i < 2; ++i) {
      int idx = i * 256 + t;
      int r = idx >> 3;
      int c4 = idx & 7;
      int grow = row0 + r;
      if (grow > NN - 1) grow = NN - 1;  // clamp, harmless re-read
      *(float4*)&xs[r][c4 * 4] = *(const float4*)&X[grow * 128 + kc + c4 * 4];
    }
    __syncthreads();
#pragma unroll
    for (int kk = 0; kk < 32; kk += 4) {
      float4 a0 = *(float4*)&xs[ty * 4 + 0][kk];
      float4 a1 = *(float4*)&xs[ty * 4 + 1][kk];
      float4 a2 = *(float4*)&xs[ty * 4 + 2][kk];
      float4 a3 = *(float4*)&xs[ty * 4 + 3][kk];
#pragma unroll
      for (int j = 0; j < 4; ++j) {
        float4 b0 = *(float4*)&ws2[kk + j][tx * 4];
        float4 b1 = *(float4*)&ws2[kk + j][64 + tx * 4];
        float a[4] = {j == 0 ? a0.x : j == 1 ? a0.y : j == 2 ? a0.z : a0.w,
                      j == 0 ? a1.x : j == 1 ? a1.y : j == 2 ? a1.z : a1.w,
                      j == 0 ? a2.x : j == 1 ? a2.y : j == 2 ? a2.z : a2.w,
                      j == 0 ? a3.x : j == 1 ? a3.y : j == 2 ? a3.z : a3.w};
#pragma unroll
        for (int i = 0; i < 4; ++i) {
          acc[i][0] += a[i] * b0.x;
          acc[i][1] += a[i] * b0.y;
          acc[i][2] += a[i] * b0.z;
          acc[i][3] += a[i] * b0.w;
          acc[i][4] += a[i] * b1.x;
          acc[i][5] += a[i] * b1.y;
          acc[i][6] += a[i] * b1.z;
          acc[i][7] += a[i] * b1.w;
        }
      }
    }
    __syncthreads();
  }
#pragma unroll
  for (int i = 0; i < 4; ++i) {
    int row = row0 + ty * 4 + i;
    if (row < NN) {
      float di = dinv[row];
      float4 o0 = make_float4(acc[i][0] * di, acc[i][1] * di, acc[i][2] * di, acc[i][3] * di);
      float4 o1 = make_float4(acc[i][4] * di, acc[i][5] * di, acc[i][6] * di, acc[i][7] * di);
      *(float4*)&G[row * 128 + tx * 4] = o0;
      *(float4*)&G[row * 128 + 64 + tx * 4] = o1;
    }
  }
}

// ---------------- aggregate: out = relu(dinv_i*(G_i + sum_{j in N(i)} G_j) + b) ----------------
// 32 lanes per node; lane owns 4 contiguous cols (float4). 4-way unrolled gather.
__global__ __launch_bounds__(256) void aggregate(const float* __restrict__ G,
                                                 const int* __restrict__ rowptr,
                                                 const int* __restrict__ col,
                                                 const float* __restrict__ dinv,
                                                 const float* __restrict__ bias,
                                                 float* __restrict__ out) {
  int gid = blockIdx.x * 256 + threadIdx.x;  // NN*32 threads, exact
  int node = gid >> 5;
  int lane = gid & 31;

  float4 acc = *(const float4*)&G[node * DD + lane * 4];  // self term

  int e = rowptr[node];
  int e1 = rowptr[node + 1];
  for (; e + 3 < e1; e += 4) {
    int s0 = col[e + 0];
    int s1 = col[e + 1];
    int s2 = col[e + 2];
    int s3 = col[e + 3];
    float4 v0 = *(const float4*)&G[s0 * DD + lane * 4];
    float4 v1 = *(const float4*)&G[s1 * DD + lane * 4];
    float4 v2 = *(const float4*)&G[s2 * DD + lane * 4];
    float4 v3 = *(const float4*)&G[s3 * DD + lane * 4];
    acc.x += v0.x + v1.x + v2.x + v3.x;
    acc.y += v0.y + v1.y + v2.y + v3.y;
    acc.z += v0.z + v1.z + v2.z + v3.z;
    acc.w += v0.w + v1.w + v2.w + v3.w;
  }
  for (; e < e1; ++e) {
    int s0 = col[e];
    float4 v0 = *(const float4*)&G[s0 * DD + lane * 4];
    acc.x += v0.x;
    acc.y += v0.y;
    acc.z += v0.z;
    acc.w += v0.w;
  }

  float di = dinv[node];
  float4 bv = *(const float4*)&bias[lane * 4];
  acc.x = fmaxf(acc.x * di + bv.x, 0.f);
  acc.y = fmaxf(acc.y * di + bv.y, 0.f);
  acc.z = fmaxf(acc.z * di + bv.z, 0.f);
  acc.w = fmaxf(acc.w * di + bv.w, 0.f);
  *(float4*)&out[node * DD + lane * 4] = acc;
}

// ---------------- launch ----------------

extern "C" void kernel_launch(void* const* d_in, const int* in_sizes, int n_in,
                              void* d_out, int out_size, void* d_ws, size_t ws_size,
                              hipStream_t stream) {
  const float* x  = (const float*)d_in[0];
  const int*   ei = (const int*)d_in[1];  // [2][NE] int32
  const float* W1 = (const float*)d_in[2];
  const float* b1 = (const float*)d_in[3];
  const float* W2 = (const float*)d_in[4];
  const float* b2 = (const float*)d_in[5];
  float* out = (float*)d_out;

  const int* esrc = ei;
  const int* edst = ei + NE;

  // workspace layout:
  char* w = (char*)d_ws;
  int*   cnt    = (int*)w;    w += ((NN + 1023) & ~1023) * 4;
  float* dinv   = (float*)w;  w += ((NN + 1023) & ~1023) * 4;
  int*   rowptr = (int*)w;    w += ((NN + 1 + 1023) & ~1023) * 4;
  int*   bsum   = (int*)w;    w += 512 * 4;
  int*   rank   = (int*)w;    w += (size_t)NE * 4;
  int*   col    = (int*)w;    w += (size_t)NE * 4;
  float* A      = (float*)w;  // NN*DD floats

  const int nb_n = (NN + 255) / 256;
  const int nb_e = (NE + 255) / 256;

  // preprocessing (shared by both layers)
  zero_i32<<<nb_n, 256, 0, stream>>>(cnt, NN);
  deg_rank<<<nb_e, 256, 0, stream>>>(edst, cnt, rank);
  scan_block_sums<<<SCAN_NB, 256, 0, stream>>>(cnt, bsum);
  scan_partials<<<1, 512, 0, stream>>>(bsum);
  scan_write<<<SCAN_NB, 256, 0, stream>>>(cnt, bsum, rowptr, dinv);
  build_csr<<<nb_e, 256, 0, stream>>>(esrc, edst, rank, rowptr, col);

  // layer 1: A = dinv*(x @ W1) ; out = relu(dinv*(A_i + sum A_j) + b1)
  gemm128<<<(NN + 63) / 64, 256, 0, stream>>>(x, W1, dinv, A);
  aggregate<<<NN * 32 / 256, 256, 0, stream>>>(A, rowptr, col, dinv, b1, out);

  // layer 2: A = dinv*(out @ W2) ; out = relu(dinv*(A_i + sum A_j) + b2)
  gemm128<<<(NN + 63) / 64, 256, 0, stream>>>(out, W2, dinv, A);
  aggregate<<<NN * 32 / 256, 256, 0, stream>>>(A, rowptr, col, dinv, b2, out);
}

// Round 6
// 421.826 us; speedup vs baseline: 13.4642x; 1.2703x over previous
//
#include <hip/hip_runtime.h>

// GCN 2-layer forward, MI355X. Round 6: bf16-compressed G for the gather
// (halves aggregate's byte traffic), fp32 accumulation everywhere.
// N=100000 nodes, E=1600000 edges, D=128 throughout.

#define NN 100000
#define NE 1600000
#define DD 128
#define SCAN_NB 391  // ceil(NN/256)

// bf16 pack/unpack helpers (round-to-nearest-even; values are finite)
__device__ __forceinline__ unsigned f2bf(float f) {
  unsigned u = __float_as_uint(f);
  return (u + 0x7fffu + ((u >> 16) & 1u)) >> 16;
}
__device__ __forceinline__ unsigned pack2(float lo, float hi) {
  return f2bf(lo) | (f2bf(hi) << 16);
}

// ---------------- degree(+rank) / scan / dinv ----------------

__global__ __launch_bounds__(256) void zero_i32(int* __restrict__ p, int n) {
  int i = blockIdx.x * 256 + threadIdx.x;
  if (i < n) p[i] = 0;
}

// rank[e] = arrival index of edge e at its destination; cnt[d] = in-degree
__global__ __launch_bounds__(256) void deg_rank(const int* __restrict__ edst,
                                                int* __restrict__ cnt,
                                                int* __restrict__ rank) {
  int e = blockIdx.x * 256 + threadIdx.x;
  if (e < NE) rank[e] = atomicAdd(&cnt[edst[e]], 1);
}

__global__ __launch_bounds__(256) void scan_block_sums(const int* __restrict__ cnt,
                                                       int* __restrict__ bsum) {
  __shared__ int s[256];
  int t = threadIdx.x;
  int i = blockIdx.x * 256 + t;
  s[t] = (i < NN) ? cnt[i] : 0;
  __syncthreads();
  for (int off = 128; off > 0; off >>= 1) {
    if (t < off) s[t] += s[t + off];
    __syncthreads();
  }
  if (t == 0) bsum[blockIdx.x] = s[0];
}

__global__ __launch_bounds__(512) void scan_partials(int* __restrict__ bsum) {
  __shared__ int s[512];
  int t = threadIdx.x;
  int v = (t < SCAN_NB) ? bsum[t] : 0;
  s[t] = v;
  __syncthreads();
  for (int off = 1; off < 512; off <<= 1) {
    int a = (t >= off) ? s[t - off] : 0;
    __syncthreads();
    s[t] += a;
    __syncthreads();
  }
  if (t < SCAN_NB) bsum[t] = s[t] - v;  // exclusive
}

// rowptr (exclusive scan) + dinv = rsqrt(deg+1), fused
__global__ __launch_bounds__(256) void scan_write(const int* __restrict__ cnt,
                                                  const int* __restrict__ bsum,
                                                  int* __restrict__ rowptr,
                                                  float* __restrict__ dinv) {
  __shared__ int s[256];
  int t = threadIdx.x;
  int i = blockIdx.x * 256 + t;
  int v = (i < NN) ? cnt[i] : 0;
  s[t] = v;
  __syncthreads();
  for (int off = 1; off < 256; off <<= 1) {
    int a = (t >= off) ? s[t - off] : 0;
    __syncthreads();
    s[t] += a;
    __syncthreads();
  }
  int excl = s[t] - v + bsum[blockIdx.x];
  if (i < NN) {
    rowptr[i] = excl;
    dinv[i] = rsqrtf((float)v + 1.0f);  // +1 = self-loop
  }
  if (i == NN - 1) rowptr[NN] = excl + v;  // == NE
}

// ---------------- CSR placement: col[rowptr[d]+rank[e]] = src (no atomics) ----------------

__global__ __launch_bounds__(256) void build_csr(const int* __restrict__ esrc,
                                                 const int* __restrict__ edst,
                                                 const int* __restrict__ rank,
                                                 const int* __restrict__ rowptr,
                                                 int* __restrict__ col) {
  int e = blockIdx.x * 256 + threadIdx.x;
  if (e < NE) col[rowptr[edst[e]] + rank[e]] = esrc[e];
}

// ---------------- GEMM: G[M,128] = bf16( dinv[m] * (X[M,128] @ W[128,128]) ) ----------------
// 64-row x 128-col tile per block (256 thr). Thread (tx=t&15, ty=t>>4):
// rows ty*4..+3, cols {tx*4..+3, 64+tx*4..+3}. K staged in chunks of 32.
__global__ __launch_bounds__(256) void gemm128(const float* __restrict__ X,
                                               const float* __restrict__ W,
                                               const float* __restrict__ dinv,
                                               unsigned short* __restrict__ G) {
  __shared__ float ws2[32][128];  // [k][c]
  __shared__ float xs[64][36];    // [r][k], stride 36 floats
  const int t = threadIdx.x;
  const int tx = t & 15;
  const int ty = t >> 4;
  const int row0 = blockIdx.x * 64;  // grid 1563, last block partially OOB
  float acc[4][8];
#pragma unroll
  for (int i = 0; i < 4; ++i)
#pragma unroll
    for (int j = 0; j < 8; ++j) acc[i][j] = 0.f;

  for (int kc = 0; kc < 128; kc += 32) {
#pragma unroll
    for (int i = 0; i < 4; ++i) {
      int idx = i * 256 + t;
      int kk = idx >> 5;
      int c4 = idx & 31;
      *(float4*)&ws2[kk][c4 * 4] = *(const float4*)&W[(kc + kk) * 128 + c4 * 4];
    }
#pragma unroll
    for (int i = 0; i < 2; ++i) {
      int idx = i * 256 + t;
      int r = idx >> 3;
      int c4 = idx & 7;
      int grow = row0 + r;
      if (grow > NN - 1) grow = NN - 1;  // clamp, harmless re-read
      *(float4*)&xs[r][c4 * 4] = *(const float4*)&X[grow * 128 + kc + c4 * 4];
    }
    __syncthreads();
#pragma unroll
    for (int kk = 0; kk < 32; kk += 4) {
      float4 a0 = *(float4*)&xs[ty * 4 + 0][kk];
      float4 a1 = *(float4*)&xs[ty * 4 + 1][kk];
      float4 a2 = *(float4*)&xs[ty * 4 + 2][kk];
      float4 a3 = *(float4*)&xs[ty * 4 + 3][kk];
#pragma unroll
      for (int j = 0; j < 4; ++j) {
        float4 b0 = *(float4*)&ws2[kk + j][tx * 4];
        float4 b1 = *(float4*)&ws2[kk + j][64 + tx * 4];
        float a[4] = {j == 0 ? a0.x : j == 1 ? a0.y : j == 2 ? a0.z : a0.w,
                      j == 0 ? a1.x : j == 1 ? a1.y : j == 2 ? a1.z : a1.w,
                      j == 0 ? a2.x : j == 1 ? a2.y : j == 2 ? a2.z : a2.w,
                      j == 0 ? a3.x : j == 1 ? a3.y : j == 2 ? a3.z : a3.w};
#pragma unroll
        for (int i = 0; i < 4; ++i) {
          acc[i][0] += a[i] * b0.x;
          acc[i][1] += a[i] * b0.y;
          acc[i][2] += a[i] * b0.z;
          acc[i][3] += a[i] * b0.w;
          acc[i][4] += a[i] * b1.x;
          acc[i][5] += a[i] * b1.y;
          acc[i][6] += a[i] * b1.z;
          acc[i][7] += a[i] * b1.w;
        }
      }
    }
    __syncthreads();
  }
#pragma unroll
  for (int i = 0; i < 4; ++i) {
    int row = row0 + ty * 4 + i;
    if (row < NN) {
      float di = dinv[row];
      uint2 p0 = make_uint2(pack2(acc[i][0] * di, acc[i][1] * di),
                            pack2(acc[i][2] * di, acc[i][3] * di));
      uint2 p1 = make_uint2(pack2(acc[i][4] * di, acc[i][5] * di),
                            pack2(acc[i][6] * di, acc[i][7] * di));
      *(uint2*)&G[row * 128 + tx * 4] = p0;
      *(uint2*)&G[row * 128 + 64 + tx * 4] = p1;
    }
  }
}

// ---------------- aggregate: out = relu(dinv_i*(G_i + sum_{j in N(i)} G_j) + b) ----------------
// 32 lanes per node; lane owns 4 contiguous cols (uint2 of bf16). fp32 accum.
__global__ __launch_bounds__(256) void aggregate(const unsigned short* __restrict__ G,
                                                 const int* __restrict__ rowptr,
                                                 const int* __restrict__ col,
                                                 const float* __restrict__ dinv,
                                                 const float* __restrict__ bias,
                                                 float* __restrict__ out) {
  int gid = blockIdx.x * 256 + threadIdx.x;  // NN*32 threads, exact
  int node = gid >> 5;
  int lane = gid & 31;
  const int off = lane * 4;

  // self term
  uint2 us = *(const uint2*)&G[node * DD + off];
  float4 acc;
  acc.x = __uint_as_float(us.x << 16);
  acc.y = __uint_as_float(us.x & 0xffff0000u);
  acc.z = __uint_as_float(us.y << 16);
  acc.w = __uint_as_float(us.y & 0xffff0000u);

  int e = rowptr[node];
  int e1 = rowptr[node + 1];
  for (; e + 3 < e1; e += 4) {
    int s0 = col[e + 0];
    int s1 = col[e + 1];
    int s2 = col[e + 2];
    int s3 = col[e + 3];
    uint2 u0 = *(const uint2*)&G[s0 * DD + off];
    uint2 u1 = *(const uint2*)&G[s1 * DD + off];
    uint2 u2 = *(const uint2*)&G[s2 * DD + off];
    uint2 u3 = *(const uint2*)&G[s3 * DD + off];
    acc.x += __uint_as_float(u0.x << 16);
    acc.y += __uint_as_float(u0.x & 0xffff0000u);
    acc.z += __uint_as_float(u0.y << 16);
    acc.w += __uint_as_float(u0.y & 0xffff0000u);
    acc.x += __uint_as_float(u1.x << 16);
    acc.y += __uint_as_float(u1.x & 0xffff0000u);
    acc.z += __uint_as_float(u1.y << 16);
    acc.w += __uint_as_float(u1.y & 0xffff0000u);
    acc.x += __uint_as_float(u2.x << 16);
    acc.y += __uint_as_float(u2.x & 0xffff0000u);
    acc.z += __uint_as_float(u2.y << 16);
    acc.w += __uint_as_float(u2.y & 0xffff0000u);
    acc.x += __uint_as_float(u3.x << 16);
    acc.y += __uint_as_float(u3.x & 0xffff0000u);
    acc.z += __uint_as_float(u3.y << 16);
    acc.w += __uint_as_float(u3.y & 0xffff0000u);
  }
  for (; e < e1; ++e) {
    int s0 = col[e];
    uint2 u0 = *(const uint2*)&G[s0 * DD + off];
    acc.x += __uint_as_float(u0.x << 16);
    acc.y += __uint_as_float(u0.x & 0xffff0000u);
    acc.z += __uint_as_float(u0.y << 16);
    acc.w += __uint_as_float(u0.y & 0xffff0000u);
  }

  float di = dinv[node];
  float4 bv = *(const float4*)&bias[off];
  acc.x = fmaxf(acc.x * di + bv.x, 0.f);
  acc.y = fmaxf(acc.y * di + bv.y, 0.f);
  acc.z = fmaxf(acc.z * di + bv.z, 0.f);
  acc.w = fmaxf(acc.w * di + bv.w, 0.f);
  *(float4*)&out[node * DD + off] = acc;
}

// ---------------- launch ----------------

extern "C" void kernel_launch(void* const* d_in, const int* in_sizes, int n_in,
                              void* d_out, int out_size, void* d_ws, size_t ws_size,
                              hipStream_t stream) {
  const float* x  = (const float*)d_in[0];
  const int*   ei = (const int*)d_in[1];  // [2][NE] int32
  const float* W1 = (const float*)d_in[2];
  const float* b1 = (const float*)d_in[3];
  const float* W2 = (const float*)d_in[4];
  const float* b2 = (const float*)d_in[5];
  float* out = (float*)d_out;

  const int* esrc = ei;
  const int* edst = ei + NE;

  // workspace layout:
  char* w = (char*)d_ws;
  int*   cnt    = (int*)w;    w += ((NN + 1023) & ~1023) * 4;
  float* dinv   = (float*)w;  w += ((NN + 1023) & ~1023) * 4;
  int*   rowptr = (int*)w;    w += ((NN + 1 + 1023) & ~1023) * 4;
  int*   bsum   = (int*)w;    w += 512 * 4;
  int*   rank   = (int*)w;    w += (size_t)NE * 4;
  int*   col    = (int*)w;    w += (size_t)NE * 4;
  unsigned short* G = (unsigned short*)w;  // NN*DD bf16

  const int nb_n = (NN + 255) / 256;
  const int nb_e = (NE + 255) / 256;

  // preprocessing (shared by both layers)
  zero_i32<<<nb_n, 256, 0, stream>>>(cnt, NN);
  deg_rank<<<nb_e, 256, 0, stream>>>(edst, cnt, rank);
  scan_block_sums<<<SCAN_NB, 256, 0, stream>>>(cnt, bsum);
  scan_partials<<<1, 512, 0, stream>>>(bsum);
  scan_write<<<SCAN_NB, 256, 0, stream>>>(cnt, bsum, rowptr, dinv);
  build_csr<<<nb_e, 256, 0, stream>>>(esrc, edst, rank, rowptr, col);

  // layer 1: G = bf16(dinv*(x @ W1)) ; out = relu(dinv*(G_i + sum G_j) + b1)
  gemm128<<<(NN + 63) / 64, 256, 0, stream>>>(x, W1, dinv, G);
  aggregate<<<NN * 32 / 256, 256, 0, stream>>>(G, rowptr, col, dinv, b1, out);

  // layer 2: G = bf16(dinv*(out @ W2)) ; out = relu(dinv*(G_i + sum G_j) + b2)
  gemm128<<<(NN + 63) / 64, 256, 0, stream>>>(out, W2, dinv, G);
  aggregate<<<NN * 32 / 256, 256, 0, stream>>>(G, rowptr, col, dinv, b2, out);
}